// Round 3
// baseline (292.415 us; speedup 1.0000x reference)
//
#include <hip/hip_runtime.h>
#include <hip/hip_bf16.h>
#include <math.h>

#define BS   128
#define NT   25
#define CREC 107
#define CLOC 25
#define QN   1024      // H*W = 32*32 queries = columns of the transposed cost
#define INFD 1e18
// swizzled index for way[] (kills stride-4 bank conflicts)
#define WSTR 257
__device__ __forceinline__ int widx(int j) {   // j in 1..QN -> [0, 1026]
    int q = j - 1;
    return (q & 3) * WSTR + (q >> 2);
}

// focal-loss matcher cost. Fast transcendentals: the matcher only needs the
// optimal assignment, robust to ~1e-7 cost perturbation (absmax 0.0 across
// many verified rounds).
__device__ __forceinline__ float focal_cost_f(float x) {
    float p   = 1.0f / (1.0f + __expf(-x));
    float neg = 0.75f * p * p * (-__logf(1.0f - p + 1e-8f));
    float pos = 0.25f * (1.0f - p) * (1.0f - p) * (-__logf(p + 1e-8f));
    return pos - neg;
}

// Dynamic-LDS layout for matcher_kernel (byte offsets; cost slab first so it
// is 16B-aligned for ds_read_b128):
//   cost_s       f32[NT*QN]   @ 0        (102400 B)
//   u_s          f64[NT+1]    @ 102400   (208 B)
//   candv_s      f64[2][4]    @ 102608   (64 B)
//   way_s        i32[4*WSTR]  @ 102672   (4112 B)   widx range [0,1026] only
//   p_s          i32[QN+1]    @ 106784   (4100 B)
//   rowmin_s     f32[NT]      @ 110884   (100 B)
//   rowarg_s     i32[NT]      @ 110984   (100 B)
//   tcs_s        i32[NT]      @ 111084   (100 B)
//   candj_s      i32[2][4]    @ 111184   (32 B)
//   nun_s        i32[1]       @ 111216   (4 B)
//   wpv_s        f32[4][NT]   @ 111220   (400 B)
//   wpa_s        i32[4][NT]   @ 111620   (400 B)
//   unassigned_s i32[NT]      @ 112020   (100 B)    DEDICATED (no aliasing!)
#define SMEM_BYTES 112128

// FUSED matcher: one block (4 waves) per batch.
// Phase 1: compute all 25 cost rows directly into the LDS slab (no global
//   cost matrix at all) while reducing per-row (min, first-argmin) exactly:
//   per-thread strict-< over its 4 owned columns, 6-step lexicographic wave
//   butterfly, cross-wave lex combine in wave order — identical ordering to
//   the old verified rowmin_kernel => identical bits.
// Phase 2: greedy tight assignment, then JV shortest-augmenting-path for
//   argmin-collided rows (~1-3/batch, ~2-4 iters each), rows read from LDS.
//   f64 duals on the same f32 cost values = exact numpy float64 JV semantics
//   => the unique optimal assignment = scipy's answer.
__global__ __launch_bounds__(256)
void matcher_kernel(const float* __restrict__ rec, const float* __restrict__ loc,
                    const int* __restrict__ targets, int* __restrict__ pairq_g,
                    int* __restrict__ counter_g) {
    const int b     = blockIdx.x;
    const int tid   = threadIdx.x;
    const int wave  = tid >> 6;
    const int lane  = tid & 63;
    const int qbase = tid << 2;          // first of the 4 owned columns

    extern __shared__ char smem_raw[];
    float*  cost_s       = (float*) (smem_raw);
    double* u_s          = (double*)(smem_raw + 102400);
    double* candv_s      = (double*)(smem_raw + 102608);   // [2][4] -> [p*4+w]
    int*    way_s        = (int*)   (smem_raw + 102672);
    int*    p_s          = (int*)   (smem_raw + 106784);
    float*  rowmin_s     = (float*) (smem_raw + 110884);
    int*    rowarg_s     = (int*)   (smem_raw + 110984);
    int*    tcs_s        = (int*)   (smem_raw + 111084);
    int*    candj_s      = (int*)   (smem_raw + 111184);   // [2][4]
    int*    nun_p        = (int*)   (smem_raw + 111216);
    float*  wpv_s        = (float*) (smem_raw + 111220);   // [4][NT]
    int*    wpa_s        = (int*)   (smem_raw + 111620);   // [4][NT]
    int*    unassigned_s = (int*)   (smem_raw + 112020);   // [NT]

    // loss/finalize last-block counter must start at 0 every iteration
    // (workspace is re-poisoned between iterations). Kernel boundary orders
    // this store before any loss_kernel block runs.
    if (b == 0 && tid == 0) counter_g[0] = 0;

    for (int j = tid; j <= QN; j += 256) p_s[j] = 0;
    if (tid < NT) tcs_s[tid] = targets[b * NT + tid];
    __syncthreads();

    // ---- phase 1: cost rows -> LDS slab + per-row exact (min, argmin) ----
    const float* recb = rec + (size_t)b * CREC * QN;
    const float* locb = loc + (size_t)b * CLOC * QN;
    #pragma unroll 5
    for (int r = 0; r < NT; ++r) {
        const int tc = tcs_s[r];
        float4 r4 = *(const float4*)(recb + ((size_t)tc << 10) + qbase);
        float4 l4 = *(const float4*)(locb + ((size_t)r  << 10) + qbase);
        float4 c;
        c.x = 2.0f * focal_cost_f(r4.x) + focal_cost_f(l4.x);
        c.y = 2.0f * focal_cost_f(r4.y) + focal_cost_f(l4.y);
        c.z = 2.0f * focal_cost_f(r4.z) + focal_cost_f(l4.z);
        c.w = 2.0f * focal_cost_f(r4.w) + focal_cost_f(l4.w);
        *(float4*)(cost_s + (r << 10) + qbase) = c;

        float bv = c.x; int bq = qbase;
        if (c.y < bv) { bv = c.y; bq = qbase + 1; }   // strict < => first index
        if (c.z < bv) { bv = c.z; bq = qbase + 2; }
        if (c.w < bv) { bv = c.w; bq = qbase + 3; }
        #pragma unroll
        for (int off = 32; off; off >>= 1) {
            float ov = __shfl_xor(bv, off);
            int   oq = __shfl_xor(bq, off);
            if (ov < bv || (ov == bv && oq < bq)) { bv = ov; bq = oq; }
        }
        if (lane == 0) { wpv_s[wave * NT + r] = bv; wpa_s[wave * NT + r] = bq; }
    }
    __syncthreads();
    if (tid < NT) {                       // cross-wave lex combine (wave order)
        float fv = wpv_s[tid]; int fq = wpa_s[tid];
        #pragma unroll
        for (int w = 1; w < 4; ++w) {
            float ov = wpv_s[w * NT + tid]; int oq = wpa_s[w * NT + tid];
            if (ov < fv || (ov == fv && oq < fq)) { fv = ov; fq = oq; }
        }
        rowmin_s[tid] = fv; rowarg_s[tid] = fq;
    }
    __syncthreads();

    // ---- greedy tight assignment (serial, trivial) ----
    if (tid == 0) {
        int nun = 0;
        for (int r = 0; r < NT; ++r) {
            u_s[r + 1] = (double)rowmin_s[r];
            int j = rowarg_s[r] + 1;
            if (p_s[j] == 0) p_s[j] = r + 1;
            else             unassigned_s[nun++] = r + 1;
        }
        nun_p[0] = nun;
    }
    __syncthreads();
    const int nun = nun_p[0];

    if (nun > 0) {
        double v[4] = {0.0, 0.0, 0.0, 0.0};

        for (int s = 0; s < nun; ++s) {
            const int i = unassigned_s[s];
            double minv[4] = {INFD, INFD, INFD, INFD};
            double snap[4] = {0.0, 0.0, 0.0, 0.0};
            double dsum    = 0.0;
            unsigned usedmask = 0;
            int j0 = 0;
            int parity = 0;

            for (;;) {
                int i0;
                if (j0 == 0) {
                    i0 = i;
                } else {
                    int q0 = j0 - 1;
                    if ((q0 >> 2) == tid) {          // owner thread of column q0
                        int m = q0 & 3;
                        usedmask |= 1u << m;
                        minv[m] = INFD;              // out of argmin & out of -=delta(free)
                        snap[m] = dsum;              // deltas before this iter don't apply
                    }
                    i0 = p_s[j0];                    // p stable within a search
                }
                const double ui0 = u_s[i0];          // pre-search value (read-only in-loop)
                const float4 c4 = *(const float4*)(cost_s + ((i0 - 1) << 10) + qbase);
                const float cf[4] = { c4.x, c4.y, c4.z, c4.w };

                // relax own free columns; lane-local lexicographic argmin (f64 exact)
                double bestv = INFD; int bestj = QN + 2;
                #pragma unroll
                for (int m = 0; m < 4; ++m) {
                    if (!(usedmask & (1u << m))) {
                        const int j = qbase + m + 1;
                        double cur = (double)cf[m] - ui0 - v[m];
                        if (cur < minv[m]) { minv[m] = cur; way_s[widx(j)] = j0; }
                        double mv = minv[m];
                        if (mv < bestv || (mv == bestv && j < bestj)) { bestv = mv; bestj = j; }
                    }
                }

                // f32-screened wave argmin: monotone screen, exact f64 resolve
                float own32 = (float)bestv;
                float w32 = own32;
                #pragma unroll
                for (int off = 32; off; off >>= 1) w32 = fminf(w32, __shfl_xor(w32, off));
                unsigned long long cand = __ballot(own32 == w32);
                double wv = INFD; int wj = QN + 2;
                while (cand) {                       // ~1 iteration typical, wave-uniform
                    int l = __ffsll(cand) - 1; cand &= cand - 1;
                    double vv = __shfl(bestv, l);
                    int    jj = __shfl(bestj, l);
                    if (vv < wv || (vv == wv && jj < wj)) { wv = vv; wj = jj; }
                }
                if (lane == 0) { candv_s[parity * 4 + wave] = wv; candj_s[parity * 4 + wave] = wj; }
                __syncthreads();                     // the ONE barrier per iteration
                double delta = candv_s[parity * 4]; int j1 = candj_s[parity * 4];
                #pragma unroll
                for (int w = 1; w < 4; ++w) {
                    double dv = candv_s[parity * 4 + w]; int dj = candj_s[parity * 4 + w];
                    if (dv < delta || (dv == delta && dj < j1)) { delta = dv; j1 = dj; }
                }
                parity ^= 1;
                dsum += delta;

                #pragma unroll
                for (int m = 0; m < 4; ++m) {
                    if (usedmask & (1u << m)) v[m]    -= delta;
                    else                      minv[m] -= delta;
                }
                j0 = j1;
                if (p_s[j0] == 0) break;
            }

            // end-of-search u updates: distinct rows => distinct LDS addrs, no race
            if (tid == 0) u_s[i] += dsum;
            unsigned mm = usedmask;
            while (mm) {
                int m = __ffs(mm) - 1; mm &= mm - 1;
                u_s[p_s[qbase + m + 1]] += dsum - snap[m];
            }
            __syncthreads();
            // augment along the alternating path (short, sequential)
            if (tid == 0) {
                int jj = j0;
                while (jj != 0) {
                    int jn = way_s[widx(jj)];
                    p_s[jj] = (jn == 0) ? i : p_s[jn];
                    jj = jn;
                }
            }
            __syncthreads();
        }
    }

    // emit matched pairs: column j assigned to target row p_s[j]-1
    for (int j = tid + 1; j <= QN; j += 256)
        if (p_s[j] > 0) pairq_g[b * NT + (p_s[j] - 1)] = j - 1;
}

// One wave per matched pair: CE over 107 (rec) and 25 (loc) classes at the
// matched query column. 3200 blocks => full latency hiding for the gathers.
// Last block to finish runs the finalize reduction (bit-identical replica of
// the old 256-thread finalize_kernel's summation tree).
__global__ __launch_bounds__(64)
void loss_kernel(const float* __restrict__ rec, const float* __restrict__ loc,
                 const int* __restrict__ targets, const int* __restrict__ pairq_g,
                 float* __restrict__ partial, int* __restrict__ counter_g,
                 float* __restrict__ out) {
    const int pid  = blockIdx.x;          // b*NT + t
    const int b    = pid / NT, t = pid % NT;
    const int lane = threadIdx.x;
    const int q    = pairq_g[pid];

    // rec CE over 107 classes at query q
    const float* rb = rec + (size_t)b * CREC * QN + q;
    float x0 = (lane < CREC)      ? rb[(size_t)lane * QN]        : -1e30f;
    float x1 = (lane + 64 < CREC) ? rb[(size_t)(lane + 64) * QN] : -1e30f;
    float mx = fmaxf(x0, x1);
    #pragma unroll
    for (int off = 32; off; off >>= 1) mx = fmaxf(mx, __shfl_xor(mx, off));
    float e = 0.0f;
    if (lane < CREC)      e += expf(x0 - mx);
    if (lane + 64 < CREC) e += expf(x1 - mx);
    #pragma unroll
    for (int off = 32; off; off >>= 1) e += __shfl_xor(e, off);
    float lse = mx + logf(e);

    // loc CE over 25 classes at query q, label = t
    const float* lb = loc + (size_t)b * CLOC * QN + q;
    float y = (lane < CLOC) ? lb[(size_t)lane * QN] : -1e30f;
    float my = y;
    #pragma unroll
    for (int off = 32; off; off >>= 1) my = fmaxf(my, __shfl_xor(my, off));
    float ey = (lane < CLOC) ? expf(y - my) : 0.0f;
    #pragma unroll
    for (int off = 32; off; off >>= 1) ey += __shfl_xor(ey, off);
    float lsey = my + logf(ey);

    if (lane == 0) {
        int lab = targets[pid];
        partial[pid]           = lse  - rb[(size_t)lab * QN];
        partial[BS * NT + pid] = lsey - lb[(size_t)t * QN];
    }

    // ---- last-block finalize (device-scope release/acquire via fences) ----
    __threadfence();                       // release our partial stores
    int tk = 0;
    if (lane == 0) tk = atomicAdd(counter_g, 1);
    tk = __shfl(tk, 0);
    if (tk == BS * NT - 1) {
        __threadfence();                   // acquire all writers' partials
        // exact replica of the old finalize: 4 virtual waves of 64 lanes
        float fs0[4], fs1[4];
        #pragma unroll
        for (int w = 0; w < 4; ++w) {
            float s0 = 0.0f, s1 = 0.0f;
            for (int i = w * 64 + lane; i < BS * NT; i += 256) {
                s0 += partial[i];
                s1 += partial[BS * NT + i];
            }
            #pragma unroll
            for (int off = 32; off; off >>= 1) {
                s0 += __shfl_xor(s0, off);
                s1 += __shfl_xor(s1, off);
            }
            fs0[w] = s0; fs1[w] = s1;      // all lanes hold the wave-w total
        }
        if (lane == 0) {
            out[0] = (((fs0[0] + fs0[1]) + fs0[2]) + fs0[3]) * (1.0f / (BS * NT));
            out[1] = (((fs1[0] + fs1[1]) + fs1[2]) + fs1[3]) * (1.0f / (BS * NT));
        }
    }
}

extern "C" void kernel_launch(void* const* d_in, const int* in_sizes, int n_in,
                              void* d_out, int out_size, void* d_ws, size_t ws_size,
                              hipStream_t stream) {
    (void)in_sizes; (void)n_in; (void)out_size; (void)ws_size;
    const float* rec     = (const float*)d_in[0];
    const float* loc     = (const float*)d_in[1];
    const int*   targets = (const int*)d_in[2];
    float* out = (float*)d_out;

    // ws layout: pairq i32[3200] | partial f32[6400] | counter i32[1]
    int*   pairq_g   = (int*)d_ws;
    float* partial   = (float*)(pairq_g + BS * NT);
    int*   counter_g = (int*)(partial + 2 * BS * NT);

    // >64KB dynamic LDS opt-in (host-side attribute; not a stream op — safe
    // under graph capture).
    static bool attr_set = false;
    if (!attr_set) {
        (void)hipFuncSetAttribute((const void*)matcher_kernel,
                                  hipFuncAttributeMaxDynamicSharedMemorySize,
                                  SMEM_BYTES);
        attr_set = true;
    }

    hipLaunchKernelGGL(matcher_kernel, dim3(BS), dim3(256), SMEM_BYTES, stream,
                       rec, loc, targets, pairq_g, counter_g);
    hipLaunchKernelGGL(loss_kernel, dim3(BS * NT), dim3(64), 0, stream,
                       rec, loc, targets, pairq_g, partial, counter_g, out);
}

// Round 4
// 169.672 us; speedup vs baseline: 1.7234x; 1.7234x over previous
//
#include <hip/hip_runtime.h>
#include <hip/hip_bf16.h>
#include <math.h>

#define BS   128
#define NT   25
#define CREC 107
#define CLOC 25
#define QN   1024      // H*W = 32*32 queries = columns of the transposed cost
#define INFD 1e18
// swizzled index for way[] (kills stride-4 bank conflicts)
#define WSTR 257
__device__ __forceinline__ int widx(int j) {   // j in 1..QN -> [0, 1026]
    int q = j - 1;
    return (q & 3) * WSTR + (q >> 2);
}

// focal-loss matcher cost. Fast transcendentals: the matcher only needs the
// optimal assignment, robust to ~1e-7 cost perturbation (absmax 0.0 across
// many verified rounds).
__device__ __forceinline__ float focal_cost_f(float x) {
    float p   = 1.0f / (1.0f + __expf(-x));
    float neg = 0.75f * p * p * (-__logf(1.0f - p + 1e-8f));
    float pos = 0.25f * (1.0f - p) * (1.0f - p) * (-__logf(p + 1e-8f));
    return pos - neg;
}

// Dynamic-LDS layout for matcher_kernel (byte offsets; cost slab first so it
// is 16B-aligned for ds_read_b128):
//   cost_s       f32[NT*QN]   @ 0        (102400 B)
//   u_s          f64[NT+1]    @ 102400   (208 B)
//   candv_s      f64[2][4]    @ 102608   (64 B)
//   way_s        i32[4*WSTR]  @ 102672   (4112 B)   widx range [0,1026] only
//   p_s          i32[QN+1]    @ 106784   (4100 B)
//   rowmin_s     f32[NT]      @ 110884   (100 B)
//   rowarg_s     i32[NT]      @ 110984   (100 B)
//   tcs_s        i32[NT]      @ 111084   (100 B)
//   candj_s      i32[2][4]    @ 111184   (32 B)
//   nun_s        i32[1]       @ 111216   (4 B)
//   wpv_s        f32[4][NT]   @ 111220   (400 B)
//   wpa_s        i32[4][NT]   @ 111620   (400 B)
//   unassigned_s i32[NT]      @ 112020   (100 B)    DEDICATED (no aliasing)
#define SMEM_BYTES 112128

// FUSED matcher (verified R3, absmax 0.0): one block (4 waves) per batch.
// Phase 1: compute all 25 cost rows directly into the LDS slab (no global
//   cost matrix at all) while reducing per-row (min, first-argmin) exactly:
//   per-thread strict-< over its 4 owned columns, 6-step lexicographic wave
//   butterfly, cross-wave lex combine in wave order — identical ordering to
//   the old verified rowmin_kernel => identical bits.
// Phase 2: greedy tight assignment, then JV shortest-augmenting-path for
//   argmin-collided rows (~1-3/batch, ~2-4 iters each), rows read from LDS.
//   f64 duals on the same f32 cost values = exact numpy float64 JV semantics
//   => the unique optimal assignment = scipy's answer.
__global__ __launch_bounds__(256)
void matcher_kernel(const float* __restrict__ rec, const float* __restrict__ loc,
                    const int* __restrict__ targets, int* __restrict__ pairq_g) {
    const int b     = blockIdx.x;
    const int tid   = threadIdx.x;
    const int wave  = tid >> 6;
    const int lane  = tid & 63;
    const int qbase = tid << 2;          // first of the 4 owned columns

    extern __shared__ char smem_raw[];
    float*  cost_s       = (float*) (smem_raw);
    double* u_s          = (double*)(smem_raw + 102400);
    double* candv_s      = (double*)(smem_raw + 102608);   // [2][4] -> [p*4+w]
    int*    way_s        = (int*)   (smem_raw + 102672);
    int*    p_s          = (int*)   (smem_raw + 106784);
    float*  rowmin_s     = (float*) (smem_raw + 110884);
    int*    rowarg_s     = (int*)   (smem_raw + 110984);
    int*    tcs_s        = (int*)   (smem_raw + 111084);
    int*    candj_s      = (int*)   (smem_raw + 111184);   // [2][4]
    int*    nun_p        = (int*)   (smem_raw + 111216);
    float*  wpv_s        = (float*) (smem_raw + 111220);   // [4][NT]
    int*    wpa_s        = (int*)   (smem_raw + 111620);   // [4][NT]
    int*    unassigned_s = (int*)   (smem_raw + 112020);   // [NT]

    for (int j = tid; j <= QN; j += 256) p_s[j] = 0;
    if (tid < NT) tcs_s[tid] = targets[b * NT + tid];
    __syncthreads();

    // ---- phase 1: cost rows -> LDS slab + per-row exact (min, argmin) ----
    const float* recb = rec + (size_t)b * CREC * QN;
    const float* locb = loc + (size_t)b * CLOC * QN;
    #pragma unroll 5
    for (int r = 0; r < NT; ++r) {
        const int tc = tcs_s[r];
        float4 r4 = *(const float4*)(recb + ((size_t)tc << 10) + qbase);
        float4 l4 = *(const float4*)(locb + ((size_t)r  << 10) + qbase);
        float4 c;
        c.x = 2.0f * focal_cost_f(r4.x) + focal_cost_f(l4.x);
        c.y = 2.0f * focal_cost_f(r4.y) + focal_cost_f(l4.y);
        c.z = 2.0f * focal_cost_f(r4.z) + focal_cost_f(l4.z);
        c.w = 2.0f * focal_cost_f(r4.w) + focal_cost_f(l4.w);
        *(float4*)(cost_s + (r << 10) + qbase) = c;

        float bv = c.x; int bq = qbase;
        if (c.y < bv) { bv = c.y; bq = qbase + 1; }   // strict < => first index
        if (c.z < bv) { bv = c.z; bq = qbase + 2; }
        if (c.w < bv) { bv = c.w; bq = qbase + 3; }
        #pragma unroll
        for (int off = 32; off; off >>= 1) {
            float ov = __shfl_xor(bv, off);
            int   oq = __shfl_xor(bq, off);
            if (ov < bv || (ov == bv && oq < bq)) { bv = ov; bq = oq; }
        }
        if (lane == 0) { wpv_s[wave * NT + r] = bv; wpa_s[wave * NT + r] = bq; }
    }
    __syncthreads();
    if (tid < NT) {                       // cross-wave lex combine (wave order)
        float fv = wpv_s[tid]; int fq = wpa_s[tid];
        #pragma unroll
        for (int w = 1; w < 4; ++w) {
            float ov = wpv_s[w * NT + tid]; int oq = wpa_s[w * NT + tid];
            if (ov < fv || (ov == fv && oq < fq)) { fv = ov; fq = oq; }
        }
        rowmin_s[tid] = fv; rowarg_s[tid] = fq;
    }
    __syncthreads();

    // ---- greedy tight assignment (serial, trivial) ----
    if (tid == 0) {
        int nun = 0;
        for (int r = 0; r < NT; ++r) {
            u_s[r + 1] = (double)rowmin_s[r];
            int j = rowarg_s[r] + 1;
            if (p_s[j] == 0) p_s[j] = r + 1;
            else             unassigned_s[nun++] = r + 1;
        }
        nun_p[0] = nun;
    }
    __syncthreads();
    const int nun = nun_p[0];

    if (nun > 0) {
        double v[4] = {0.0, 0.0, 0.0, 0.0};

        for (int s = 0; s < nun; ++s) {
            const int i = unassigned_s[s];
            double minv[4] = {INFD, INFD, INFD, INFD};
            double snap[4] = {0.0, 0.0, 0.0, 0.0};
            double dsum    = 0.0;
            unsigned usedmask = 0;
            int j0 = 0;
            int parity = 0;

            for (;;) {
                int i0;
                if (j0 == 0) {
                    i0 = i;
                } else {
                    int q0 = j0 - 1;
                    if ((q0 >> 2) == tid) {          // owner thread of column q0
                        int m = q0 & 3;
                        usedmask |= 1u << m;
                        minv[m] = INFD;              // out of argmin & out of -=delta(free)
                        snap[m] = dsum;              // deltas before this iter don't apply
                    }
                    i0 = p_s[j0];                    // p stable within a search
                }
                const double ui0 = u_s[i0];          // pre-search value (read-only in-loop)
                const float4 c4 = *(const float4*)(cost_s + ((i0 - 1) << 10) + qbase);
                const float cf[4] = { c4.x, c4.y, c4.z, c4.w };

                // relax own free columns; lane-local lexicographic argmin (f64 exact)
                double bestv = INFD; int bestj = QN + 2;
                #pragma unroll
                for (int m = 0; m < 4; ++m) {
                    if (!(usedmask & (1u << m))) {
                        const int j = qbase + m + 1;
                        double cur = (double)cf[m] - ui0 - v[m];
                        if (cur < minv[m]) { minv[m] = cur; way_s[widx(j)] = j0; }
                        double mv = minv[m];
                        if (mv < bestv || (mv == bestv && j < bestj)) { bestv = mv; bestj = j; }
                    }
                }

                // f32-screened wave argmin: monotone screen, exact f64 resolve
                float own32 = (float)bestv;
                float w32 = own32;
                #pragma unroll
                for (int off = 32; off; off >>= 1) w32 = fminf(w32, __shfl_xor(w32, off));
                unsigned long long cand = __ballot(own32 == w32);
                double wv = INFD; int wj = QN + 2;
                while (cand) {                       // ~1 iteration typical, wave-uniform
                    int l = __ffsll(cand) - 1; cand &= cand - 1;
                    double vv = __shfl(bestv, l);
                    int    jj = __shfl(bestj, l);
                    if (vv < wv || (vv == wv && jj < wj)) { wv = vv; wj = jj; }
                }
                if (lane == 0) { candv_s[parity * 4 + wave] = wv; candj_s[parity * 4 + wave] = wj; }
                __syncthreads();                     // the ONE barrier per iteration
                double delta = candv_s[parity * 4]; int j1 = candj_s[parity * 4];
                #pragma unroll
                for (int w = 1; w < 4; ++w) {
                    double dv = candv_s[parity * 4 + w]; int dj = candj_s[parity * 4 + w];
                    if (dv < delta || (dv == delta && dj < j1)) { delta = dv; j1 = dj; }
                }
                parity ^= 1;
                dsum += delta;

                #pragma unroll
                for (int m = 0; m < 4; ++m) {
                    if (usedmask & (1u << m)) v[m]    -= delta;
                    else                      minv[m] -= delta;
                }
                j0 = j1;
                if (p_s[j0] == 0) break;
            }

            // end-of-search u updates: distinct rows => distinct LDS addrs, no race
            if (tid == 0) u_s[i] += dsum;
            unsigned mm = usedmask;
            while (mm) {
                int m = __ffs(mm) - 1; mm &= mm - 1;
                u_s[p_s[qbase + m + 1]] += dsum - snap[m];
            }
            __syncthreads();
            // augment along the alternating path (short, sequential)
            if (tid == 0) {
                int jj = j0;
                while (jj != 0) {
                    int jn = way_s[widx(jj)];
                    p_s[jj] = (jn == 0) ? i : p_s[jn];
                    jj = jn;
                }
            }
            __syncthreads();
        }
    }

    // emit matched pairs: column j assigned to target row p_s[j]-1
    for (int j = tid + 1; j <= QN; j += 256)
        if (p_s[j] > 0) pairq_g[b * NT + (p_s[j] - 1)] = j - 1;
}

// One wave per matched pair: CE over 107 (rec) and 25 (loc) classes at the
// matched query column. 3200 blocks => full latency hiding for the gathers.
// NO fences/atomics here — R3 showed per-block __threadfence() costs ~130 µs
// (3200 device-scope L2 flushes on non-coherent XCD L2s). The cross-kernel
// handoff to finalize_kernel does the cache maintenance ONCE at the boundary.
__global__ __launch_bounds__(64)
void loss_kernel(const float* __restrict__ rec, const float* __restrict__ loc,
                 const int* __restrict__ targets, const int* __restrict__ pairq_g,
                 float* __restrict__ partial) {
    const int pid  = blockIdx.x;          // b*NT + t
    const int b    = pid / NT, t = pid % NT;
    const int lane = threadIdx.x;
    const int q    = pairq_g[pid];

    // rec CE over 107 classes at query q
    const float* rb = rec + (size_t)b * CREC * QN + q;
    float x0 = (lane < CREC)      ? rb[(size_t)lane * QN]        : -1e30f;
    float x1 = (lane + 64 < CREC) ? rb[(size_t)(lane + 64) * QN] : -1e30f;
    float mx = fmaxf(x0, x1);
    #pragma unroll
    for (int off = 32; off; off >>= 1) mx = fmaxf(mx, __shfl_xor(mx, off));
    float e = 0.0f;
    if (lane < CREC)      e += expf(x0 - mx);
    if (lane + 64 < CREC) e += expf(x1 - mx);
    #pragma unroll
    for (int off = 32; off; off >>= 1) e += __shfl_xor(e, off);
    float lse = mx + logf(e);

    // loc CE over 25 classes at query q, label = t
    const float* lb = loc + (size_t)b * CLOC * QN + q;
    float y = (lane < CLOC) ? lb[(size_t)lane * QN] : -1e30f;
    float my = y;
    #pragma unroll
    for (int off = 32; off; off >>= 1) my = fmaxf(my, __shfl_xor(my, off));
    float ey = (lane < CLOC) ? expf(y - my) : 0.0f;
    #pragma unroll
    for (int off = 32; off; off >>= 1) ey += __shfl_xor(ey, off);
    float lsey = my + logf(ey);

    if (lane == 0) {
        int lab = targets[pid];
        partial[pid]           = lse  - rb[(size_t)lab * QN];
        partial[BS * NT + pid] = lsey - lb[(size_t)t * QN];
    }
}

__global__ __launch_bounds__(256)
void finalize_kernel(const float* __restrict__ partial, float* __restrict__ out) {
    const int tid = threadIdx.x;
    float s0 = 0.0f, s1 = 0.0f;
    for (int i = tid; i < BS * NT; i += 256) {
        s0 += partial[i];
        s1 += partial[BS * NT + i];
    }
    __shared__ float a0[4], a1[4];
    #pragma unroll
    for (int off = 32; off; off >>= 1) { s0 += __shfl_xor(s0, off); s1 += __shfl_xor(s1, off); }
    if ((tid & 63) == 0) { a0[tid >> 6] = s0; a1[tid >> 6] = s1; }
    __syncthreads();
    if (tid == 0) {
        out[0] = (a0[0] + a0[1] + a0[2] + a0[3]) * (1.0f / (BS * NT));
        out[1] = (a1[0] + a1[1] + a1[2] + a1[3]) * (1.0f / (BS * NT));
    }
}

extern "C" void kernel_launch(void* const* d_in, const int* in_sizes, int n_in,
                              void* d_out, int out_size, void* d_ws, size_t ws_size,
                              hipStream_t stream) {
    (void)in_sizes; (void)n_in; (void)out_size; (void)ws_size;
    const float* rec     = (const float*)d_in[0];
    const float* loc     = (const float*)d_in[1];
    const int*   targets = (const int*)d_in[2];
    float* out = (float*)d_out;

    // ws layout: pairq i32[3200] | partial f32[6400]
    int*   pairq_g = (int*)d_ws;
    float* partial = (float*)(pairq_g + BS * NT);

    // >64KB dynamic LDS opt-in (host-side attribute; not a stream op — safe
    // under graph capture).
    static bool attr_set = false;
    if (!attr_set) {
        (void)hipFuncSetAttribute((const void*)matcher_kernel,
                                  hipFuncAttributeMaxDynamicSharedMemorySize,
                                  SMEM_BYTES);
        attr_set = true;
    }

    hipLaunchKernelGGL(matcher_kernel, dim3(BS), dim3(256), SMEM_BYTES, stream,
                       rec, loc, targets, pairq_g);
    hipLaunchKernelGGL(loss_kernel, dim3(BS * NT), dim3(64), 0, stream,
                       rec, loc, targets, pairq_g, partial);
    hipLaunchKernelGGL(finalize_kernel, dim3(1), dim3(256), 0, stream,
                       partial, out);
}

// Round 5
// 142.958 us; speedup vs baseline: 2.0455x; 1.1869x over previous
//
#include <hip/hip_runtime.h>
#include <hip/hip_bf16.h>
#include <math.h>

#define BS   128
#define NT   25
#define CREC 107
#define CLOC 25
#define QN   1024      // H*W = 32*32 queries = columns of the transposed cost
#define INFD 1e18

// focal-loss matcher cost. Fast transcendentals: the matcher only needs the
// optimal assignment, robust to ~1e-7 cost perturbation (absmax 0.0 across
// many verified rounds).
__device__ __forceinline__ float focal_cost_f(float x) {
    float p   = 1.0f / (1.0f + __expf(-x));
    float neg = 0.75f * p * p * (-__logf(1.0f - p + 1e-8f));
    float pos = 0.25f * (1.0f - p) * (1.0f - p) * (-__logf(p + 1e-8f));
    return pos - neg;
}

// One block per cost row (b,r): computes the row's costs, STORES them to
// global (L3-hot for search), and reduces min + first-index argmin exactly.
// 3200 blocks => full memory-latency hiding (R4 showed 128-block fusion of
// this phase costs ~40 us; this form is ~8 us).
__global__ __launch_bounds__(256)
void rowmin_kernel(const float* __restrict__ rec, const float* __restrict__ loc,
                   const int* __restrict__ targets, float* __restrict__ cost_g,
                   float* __restrict__ rowmin_g, int* __restrict__ rowarg_g) {
    const int pid   = blockIdx.x;          // b*NT + r
    const int b     = pid / NT, r = pid % NT;
    const int tid   = threadIdx.x;
    const int qbase = tid << 2;
    const int tc    = targets[pid];

    float4 r4 = *(const float4*)(rec + ((size_t)b * CREC + tc) * QN + qbase);
    float4 l4 = *(const float4*)(loc + ((size_t)b * CLOC + r)  * QN + qbase);
    float4 c;
    c.x = 2.0f * focal_cost_f(r4.x) + focal_cost_f(l4.x);
    c.y = 2.0f * focal_cost_f(r4.y) + focal_cost_f(l4.y);
    c.z = 2.0f * focal_cost_f(r4.z) + focal_cost_f(l4.z);
    c.w = 2.0f * focal_cost_f(r4.w) + focal_cost_f(l4.w);
    *(float4*)(cost_g + ((size_t)pid << 10) + qbase) = c;

    float bv = c.x; int bq = qbase;
    if (c.y < bv) { bv = c.y; bq = qbase + 1; }     // strict < => first index
    if (c.z < bv) { bv = c.z; bq = qbase + 2; }
    if (c.w < bv) { bv = c.w; bq = qbase + 3; }
    #pragma unroll
    for (int off = 32; off; off >>= 1) {
        float ov = __shfl_xor(bv, off);
        int   oq = __shfl_xor(bq, off);
        if (ov < bv || (ov == bv && oq < bq)) { bv = ov; bq = oq; }
    }
    __shared__ float bmv[4];
    __shared__ int   bmq[4];
    if ((tid & 63) == 0) { bmv[tid >> 6] = bv; bmq[tid >> 6] = bq; }
    __syncthreads();
    if (tid == 0) {
        float fv = bmv[0]; int fq = bmq[0];
        #pragma unroll
        for (int w = 1; w < 4; ++w) {
            float ov = bmv[w]; int oq = bmq[w];
            if (ov < fv || (ov == fv && oq < fq)) { fv = ov; fq = oq; }
        }
        rowmin_g[pid] = fv; rowarg_g[pid] = fq;
    }
}

// ONE WAVE (64 threads) per batch: greedy tight assignment from row minima,
// then JV shortest-augmenting-path for argmin-collided rows. Thread t owns
// columns c == t (mod 64), 16 slots each:
//  - cost-row reads from cost_g are coalesced per slot-step (lanes read
//    consecutive dwords), L3-hot from rowmin's store;
//  - way_s/p_s are linear (2-way LDS bank aliasing across 64 lanes = free);
//  - the wave argmin is the ENTIRE argmin: f32-monotone screen butterfly +
//    ballot + exact-f64 resolve in all lanes => every lane holds the exact
//    global lexicographic (delta, j1). No cross-wave LDS combine, no
//    __syncthreads anywhere in the search loop => the serial per-iteration
//    chain loses its barrier/combine segment.
// Same algorithm semantics as the verified R0 kernel: strict-< relax,
// snap/dsum dual bookkeeping, f64 duals on the same f32 cost values = exact
// numpy float64 JV => the unique optimal assignment = scipy's answer.
__global__ __launch_bounds__(64)
void search_kernel(const float* __restrict__ cost_g,
                   const float* __restrict__ rowmin_g, const int* __restrict__ rowarg_g,
                   int* __restrict__ pairq_g) {
    const int b    = blockIdx.x;
    const int lane = threadIdx.x;        // 0..63

    __shared__ int    way_s[QN + 1];
    __shared__ int    p_s[QN + 1];
    __shared__ double u_s[NT + 1];
    __shared__ float  rowmin_s[NT];
    __shared__ int    rowarg_s[NT];
    __shared__ int    unassigned_s[NT];
    __shared__ int    nun_s;

    for (int j = lane; j <= QN; j += 64) p_s[j] = 0;
    if (lane < NT) {
        rowmin_s[lane] = rowmin_g[b * NT + lane];
        rowarg_s[lane] = rowarg_g[b * NT + lane];
    }
    __syncthreads();

    // greedy tight assignment (serial, trivial)
    if (lane == 0) {
        int nun = 0;
        for (int r = 0; r < NT; ++r) {
            u_s[r + 1] = (double)rowmin_s[r];
            int j = rowarg_s[r] + 1;
            if (p_s[j] == 0) p_s[j] = r + 1;
            else             unassigned_s[nun++] = r + 1;
        }
        nun_s = nun;
    }
    __syncthreads();
    const int nun = nun_s;

    if (nun > 0) {
        const float* cb = cost_g + ((size_t)b * NT << 10);
        double v[16];
        #pragma unroll
        for (int m = 0; m < 16; ++m) v[m] = 0.0;

        for (int s = 0; s < nun; ++s) {
            const int i = unassigned_s[s];
            double minv[16], snap[16];
            #pragma unroll
            for (int m = 0; m < 16; ++m) { minv[m] = INFD; snap[m] = 0.0; }
            double dsum = 0.0;
            unsigned usedmask = 0;
            int j0 = 0;

            for (;;) {
                int i0;
                if (j0 == 0) {
                    i0 = i;
                } else {
                    int q0 = j0 - 1;
                    if ((q0 & 63) == lane) {         // owner lane of column q0
                        int mm = q0 >> 6;
                        usedmask |= 1u << mm;
                        #pragma unroll                // static indices only
                        for (int m = 0; m < 16; ++m)
                            if (m == mm) { minv[m] = INFD; snap[m] = dsum; }
                    }
                    i0 = p_s[j0];                    // p stable within a search
                }
                const double ui0 = u_s[i0];          // pre-search value (read-only in-loop)
                const float* rowp = cb + ((size_t)(i0 - 1) << 10);
                float cf[16];
                #pragma unroll                        // coalesced: lanes read consecutive dwords
                for (int m = 0; m < 16; ++m) cf[m] = rowp[(m << 6) + lane];

                // relax own free columns; lane-local lexicographic argmin
                // (ascending m == ascending j within a lane)
                double bestv = INFD; int bestj = QN + 2;
                #pragma unroll
                for (int m = 0; m < 16; ++m) {
                    if (!(usedmask & (1u << m))) {
                        const int j = (m << 6) + lane + 1;
                        double cur = (double)cf[m] - ui0 - v[m];
                        if (cur < minv[m]) { minv[m] = cur; way_s[j] = j0; }
                        double mv = minv[m];
                        if (mv < bestv || (mv == bestv && j < bestj)) { bestv = mv; bestj = j; }
                    }
                }

                // f32-screened wave argmin over ALL 64 lanes: monotone screen,
                // exact f64 resolve; every lane ends with the global (wv, wj).
                float own32 = (float)bestv;
                float w32 = own32;
                #pragma unroll
                for (int off = 32; off; off >>= 1) w32 = fminf(w32, __shfl_xor(w32, off));
                unsigned long long cand = __ballot(own32 == w32);
                double wv = INFD; int wj = QN + 2;
                while (cand) {                       // ~1 iteration typical, wave-uniform
                    int l = __ffsll(cand) - 1; cand &= cand - 1;
                    double vv = __shfl(bestv, l);
                    int    jj = __shfl(bestj, l);
                    if (vv < wv || (vv == wv && jj < wj)) { wv = vv; wj = jj; }
                }
                const double delta = wv; const int j1 = wj;
                dsum += delta;

                #pragma unroll
                for (int m = 0; m < 16; ++m) {
                    if (usedmask & (1u << m)) v[m]    -= delta;
                    else                      minv[m] -= delta;
                }
                j0 = j1;
                if (p_s[j0] == 0) break;
            }

            // end-of-search u updates: distinct used columns => distinct
            // assigned rows => distinct LDS addresses, no race
            if (lane == 0) u_s[i] += dsum;
            unsigned mm = usedmask;
            while (mm) {
                int m = __ffs(mm) - 1; mm &= mm - 1;
                u_s[p_s[(m << 6) + lane + 1]] += dsum - snap[m];
            }
            __syncthreads();   // way_s/u_s visible to lane 0 (1-wave: cheap)
            // augment along the alternating path (short, sequential)
            if (lane == 0) {
                int jj = j0;
                while (jj != 0) {
                    int jn = way_s[jj];
                    p_s[jj] = (jn == 0) ? i : p_s[jn];
                    jj = jn;
                }
            }
            __syncthreads();   // p_s visible to all lanes for next search
        }
    }

    // emit matched pairs: column j assigned to target row p_s[j]-1
    for (int j = lane + 1; j <= QN; j += 64)
        if (p_s[j] > 0) pairq_g[b * NT + (p_s[j] - 1)] = j - 1;
}

// One wave per matched pair: CE over 107 (rec) and 25 (loc) classes at the
// matched query column. 3200 blocks => full latency hiding for the gathers.
// NO fences/atomics here — R3 showed per-block __threadfence() costs ~130 us
// (3200 device-scope flushes on non-coherent XCD L2s). The cross-kernel
// handoff to finalize_kernel does the cache maintenance ONCE at the boundary.
__global__ __launch_bounds__(64)
void loss_kernel(const float* __restrict__ rec, const float* __restrict__ loc,
                 const int* __restrict__ targets, const int* __restrict__ pairq_g,
                 float* __restrict__ partial) {
    const int pid  = blockIdx.x;          // b*NT + t
    const int b    = pid / NT, t = pid % NT;
    const int lane = threadIdx.x;
    const int q    = pairq_g[pid];

    // rec CE over 107 classes at query q
    const float* rb = rec + (size_t)b * CREC * QN + q;
    float x0 = (lane < CREC)      ? rb[(size_t)lane * QN]        : -1e30f;
    float x1 = (lane + 64 < CREC) ? rb[(size_t)(lane + 64) * QN] : -1e30f;
    float mx = fmaxf(x0, x1);
    #pragma unroll
    for (int off = 32; off; off >>= 1) mx = fmaxf(mx, __shfl_xor(mx, off));
    float e = 0.0f;
    if (lane < CREC)      e += expf(x0 - mx);
    if (lane + 64 < CREC) e += expf(x1 - mx);
    #pragma unroll
    for (int off = 32; off; off >>= 1) e += __shfl_xor(e, off);
    float lse = mx + logf(e);

    // loc CE over 25 classes at query q, label = t
    const float* lb = loc + (size_t)b * CLOC * QN + q;
    float y = (lane < CLOC) ? lb[(size_t)lane * QN] : -1e30f;
    float my = y;
    #pragma unroll
    for (int off = 32; off; off >>= 1) my = fmaxf(my, __shfl_xor(my, off));
    float ey = (lane < CLOC) ? expf(y - my) : 0.0f;
    #pragma unroll
    for (int off = 32; off; off >>= 1) ey += __shfl_xor(ey, off);
    float lsey = my + logf(ey);

    if (lane == 0) {
        int lab = targets[pid];
        partial[pid]           = lse  - rb[(size_t)lab * QN];
        partial[BS * NT + pid] = lsey - lb[(size_t)t * QN];
    }
}

__global__ __launch_bounds__(256)
void finalize_kernel(const float* __restrict__ partial, float* __restrict__ out) {
    const int tid = threadIdx.x;
    float s0 = 0.0f, s1 = 0.0f;
    for (int i = tid; i < BS * NT; i += 256) {
        s0 += partial[i];
        s1 += partial[BS * NT + i];
    }
    __shared__ float a0[4], a1[4];
    #pragma unroll
    for (int off = 32; off; off >>= 1) { s0 += __shfl_xor(s0, off); s1 += __shfl_xor(s1, off); }
    if ((tid & 63) == 0) { a0[tid >> 6] = s0; a1[tid >> 6] = s1; }
    __syncthreads();
    if (tid == 0) {
        out[0] = (a0[0] + a0[1] + a0[2] + a0[3]) * (1.0f / (BS * NT));
        out[1] = (a1[0] + a1[1] + a1[2] + a1[3]) * (1.0f / (BS * NT));
    }
}

extern "C" void kernel_launch(void* const* d_in, const int* in_sizes, int n_in,
                              void* d_out, int out_size, void* d_ws, size_t ws_size,
                              hipStream_t stream) {
    (void)in_sizes; (void)n_in; (void)out_size; (void)ws_size;
    const float* rec     = (const float*)d_in[0];
    const float* loc     = (const float*)d_in[1];
    const int*   targets = (const int*)d_in[2];
    float* out = (float*)d_out;

    // ws layout: cost f32[BS*NT*QN]=13.1MB | rowmin f32[3200] | rowarg i32[3200]
    //            | pairq i32[3200] | partial f32[6400]
    float* cost_g   = (float*)d_ws;
    float* rowmin_g = cost_g + (size_t)BS * NT * QN;
    int*   rowarg_g = (int*)(rowmin_g + BS * NT);
    int*   pairq_g  = rowarg_g + BS * NT;
    float* partial  = (float*)(pairq_g + BS * NT);

    hipLaunchKernelGGL(rowmin_kernel, dim3(BS * NT), dim3(256), 0, stream,
                       rec, loc, targets, cost_g, rowmin_g, rowarg_g);
    hipLaunchKernelGGL(search_kernel, dim3(BS), dim3(64), 0, stream,
                       cost_g, rowmin_g, rowarg_g, pairq_g);
    hipLaunchKernelGGL(loss_kernel, dim3(BS * NT), dim3(64), 0, stream,
                       rec, loc, targets, pairq_g, partial);
    hipLaunchKernelGGL(finalize_kernel, dim3(1), dim3(256), 0, stream,
                       partial, out);
}